// Round 1
// baseline (456.224 us; speedup 1.0000x reference)
//
#include <hip/hip_runtime.h>

// BarrierNet fused MLP + CBF-QP filter, fp32 baseline.
// One thread per batch row. Weights read via wave-uniform global loads
// (expected to scalarize to s_load_*), activations in registers.

__device__ __forceinline__ float fast_sigmoid(float z) {
    // 1/(1+exp(-z)); v_exp_f32 + v_rcp_f32. Overflow-safe: exp->inf -> rcp->0.
    return __builtin_amdgcn_rcpf(1.0f + __expf(-z));
}

__global__ __launch_bounds__(256) void barriernet_kernel(
    const float* __restrict__ obs,
    const float* __restrict__ W1,  const float* __restrict__ b1,
    const float* __restrict__ W21, const float* __restrict__ b21,
    const float* __restrict__ W22, const float* __restrict__ b22,
    const float* __restrict__ W31, const float* __restrict__ b31,
    const float* __restrict__ W32, const float* __restrict__ b32,
    float* __restrict__ out, int B)
{
    const int row = blockIdx.x * 256 + threadIdx.x;
    if (row >= B) return;

    // obs row: 10 floats, 8B-aligned (row*40 bytes) -> five float2 loads.
    float o[10];
    const float2* o2 = reinterpret_cast<const float2*>(obs + (size_t)row * 10);
    #pragma unroll
    for (int i = 0; i < 5; ++i) {
        float2 v = o2[i];
        o[2 * i]     = v.x;
        o[2 * i + 1] = v.y;
    }

    // Accumulators for the two 128->32 branches (fp32, bias-initialized).
    float acc21[32], acc22[32];
    #pragma unroll
    for (int j = 0; j < 32; ++j) acc21[j] = b21[j];
    #pragma unroll
    for (int j = 0; j < 32; ++j) acc22[j] = b22[j];

    // Layer 1 (10->128) fused with layer 2 accumulation, tiled 16 hidden
    // units at a time to bound register pressure. t-loop stays rolled
    // (uniform weight addresses, smaller I-footprint); inner loops unrolled
    // so register arrays keep constant indices.
    for (int t = 0; t < 8; ++t) {
        float xt[16];
        #pragma unroll
        for (int i = 0; i < 16; ++i) {
            const int j = t * 16 + i;
            float z = b1[j];
            #pragma unroll
            for (int f = 0; f < 10; ++f)
                z = fmaf(o[f], W1[j * 10 + f], z);   // W1 is [128,10] row-major
            xt[i] = z * fast_sigmoid(z);             // silu
        }
        const float* w21t = W21 + t * 16;            // W21 is [32,128]
        const float* w22t = W22 + t * 16;
        #pragma unroll
        for (int oo = 0; oo < 32; ++oo) {
            float a = acc21[oo];
            #pragma unroll
            for (int i = 0; i < 16; ++i)
                a = fmaf(xt[i], w21t[oo * 128 + i], a);  // 16 consecutive weights -> s_load_dwordx16
            acc21[oo] = a;
        }
        #pragma unroll
        for (int oo = 0; oo < 32; ++oo) {
            float a = acc22[oo];
            #pragma unroll
            for (int i = 0; i < 16; ++i)
                a = fmaf(xt[i], w22t[oo * 128 + i], a);
            acc22[oo] = a;
        }
    }

    // Heads: unom = silu(acc21) @ W31^T + b31 ; z32 = silu(acc22) @ W32^T + b32
    float u0 = b31[0], u1 = b31[1], z32 = b32[0];
    #pragma unroll
    for (int j = 0; j < 32; ++j) {
        float z = acc21[j];
        float s = z * fast_sigmoid(z);
        u0 = fmaf(s, W31[j], u0);        // W31 is [2,32]
        u1 = fmaf(s, W31[32 + j], u1);
    }
    #pragma unroll
    for (int j = 0; j < 32; ++j) {
        float z = acc22[j];
        float s = z * fast_sigmoid(z);
        z32 = fmaf(s, W32[j], z32);      // W32 is [1,32]
    }
    const float alpha = 4.0f * fast_sigmoid(z32);

    // CBF-QP epilogue (R_SAFE = 0.8).
    const float rx = o[6], ry = o[7], vx = o[8], vy = o[9];
    const float barrier = rx * rx + ry * ry - 0.64f;
    const float lf = -2.0f * (rx * vx + ry * vy);
    const float gx = -2.0f * rx, gy = -2.0f * ry;
    const float h  = lf + alpha * barrier;
    const float gg = gx * gx + gy * gy;
    const float viol = gx * u0 + gy * u1 - h;
    float lam = 0.0f;
    if (gg > 0.0f) lam = fmaxf(viol, 0.0f) / fmaxf(gg, 1e-12f);

    float2 r;
    r.x = fmaf(-lam, gx, u0);
    r.y = fmaf(-lam, gy, u1);
    *reinterpret_cast<float2*>(out + (size_t)row * 2) = r;
}

extern "C" void kernel_launch(void* const* d_in, const int* in_sizes, int n_in,
                              void* d_out, int out_size, void* d_ws, size_t ws_size,
                              hipStream_t stream) {
    const float* obs = (const float*)d_in[0];
    const float* W1  = (const float*)d_in[1];
    const float* b1  = (const float*)d_in[2];
    const float* W21 = (const float*)d_in[3];
    const float* b21 = (const float*)d_in[4];
    const float* W22 = (const float*)d_in[5];
    const float* b22 = (const float*)d_in[6];
    const float* W31 = (const float*)d_in[7];
    const float* b31 = (const float*)d_in[8];
    const float* W32 = (const float*)d_in[9];
    const float* b32 = (const float*)d_in[10];

    const int B = in_sizes[0] / 10;           // obs is [B,10]
    const int blocks = (B + 255) / 256;       // B = 524288 -> 2048 blocks

    barriernet_kernel<<<blocks, 256, 0, stream>>>(
        obs, W1, b1, W21, b21, W22, b22, W31, b31, W32, b32,
        (float*)d_out, B);
}

// Round 2
// 350.369 us; speedup vs baseline: 1.3021x; 1.3021x over previous
//
#include <hip/hip_runtime.h>

// BarrierNet fused MLP + CBF-QP filter, fp32, LDS-staged weights.
// One thread per row. All weights (~39 KB) cooperatively staged into LDS once
// per block; compute reads them with wave-uniform addresses (ds broadcast,
// no bank conflicts) and compile-time immediate offsets, so per-FMA overhead
// is ~zero. Control flow is fully uniform (row clamp instead of early return)
// so no divergence and no barrier hazards.

#define TPB 256

// LDS float offsets. W1 rows padded 10->12 floats so every row is 16B-aligned.
#define oW1  0        // [128][12] padded            (1536 floats)
#define oB1  1536     // [128]
#define oW21 1664     // [32][128]                   (4096)
#define oB21 5760     // [32]
#define oW22 5792     // [32][128]                   (4096)
#define oB22 9888     // [32]
#define oW31 9920     // [2][32]                     (64)
#define oB31 9984     // [2]  (+2 pad for alignment)
#define oW32 9988     // [32]
#define oB32 10020    // [1]
#define SMEM_F 10024  // 40096 bytes -> 4 blocks/CU (160 KiB LDS)

__device__ __forceinline__ float fast_sigmoid(float z) {
    // 1/(1+exp(-z)); v_exp_f32 + v_rcp_f32. Overflow-safe: exp->inf -> rcp->0.
    return __builtin_amdgcn_rcpf(1.0f + __expf(-z));
}

__global__ __launch_bounds__(TPB) void barriernet_kernel(
    const float* __restrict__ obs,
    const float* __restrict__ W1,  const float* __restrict__ b1,
    const float* __restrict__ W21, const float* __restrict__ b21,
    const float* __restrict__ W22, const float* __restrict__ b22,
    const float* __restrict__ W31, const float* __restrict__ b31,
    const float* __restrict__ W32, const float* __restrict__ b32,
    float* __restrict__ out, int B)
{
    __shared__ float s[SMEM_F];
    const int tid = threadIdx.x;

    // Uniform control flow: clamp instead of return. Duplicate threads (only
    // when B % TPB != 0) recompute the last row and store identical values.
    int row = blockIdx.x * TPB + tid;
    if (row >= B) row = B - 1;           // compiles to v_min; no branch

    // Kick off the per-row obs load early (5x float2, 8B-aligned: row*40 B).
    float o[10];
    const float2* o2 = reinterpret_cast<const float2*>(obs + (size_t)row * 10);
    #pragma unroll
    for (int i = 0; i < 5; ++i) {
        float2 v = o2[i];
        o[2 * i]     = v.x;
        o[2 * i + 1] = v.y;
    }

    // ---- Cooperative weight staging into LDS ----
    for (int i = tid; i < 1280; i += TPB) s[oW1 + (i / 10) * 12 + (i % 10)] = W1[i];
    for (int i = tid; i < 128;  i += TPB) s[oB1  + i] = b1[i];
    for (int i = tid; i < 4096; i += TPB) s[oW21 + i] = W21[i];
    for (int i = tid; i < 32;   i += TPB) s[oB21 + i] = b21[i];
    for (int i = tid; i < 4096; i += TPB) s[oW22 + i] = W22[i];
    for (int i = tid; i < 32;   i += TPB) s[oB22 + i] = b22[i];
    for (int i = tid; i < 64;   i += TPB) s[oW31 + i] = W31[i];
    for (int i = tid; i < 2;    i += TPB) s[oB31 + i] = b31[i];
    for (int i = tid; i < 32;   i += TPB) s[oW32 + i] = W32[i];
    if (tid == 0) s[oB32] = b32[0];
    __syncthreads();

    // ---- Compute ----
    float acc21[32], acc22[32];
    #pragma unroll
    for (int j = 0; j < 32; ++j) acc21[j] = s[oB21 + j];
    #pragma unroll
    for (int j = 0; j < 32; ++j) acc22[j] = s[oB22 + j];

    // Layer 1 (10->128) fused with layer 2 (128->32 x2), 16 hidden units/iter.
    // All LDS reads are wave-uniform -> broadcast, zero bank conflicts.
    for (int t = 0; t < 8; ++t) {
        float xt[16];
        const float* w1t = s + oW1 + t * (16 * 12);
        #pragma unroll
        for (int i = 0; i < 16; ++i) {
            const float* wr = w1t + i * 12;          // 48B stride: 16B-aligned
            float4 wa = *reinterpret_cast<const float4*>(wr);
            float4 wb = *reinterpret_cast<const float4*>(wr + 4);
            float2 wc = *reinterpret_cast<const float2*>(wr + 8);
            float z = s[oB1 + t * 16 + i];
            z = fmaf(o[0], wa.x, z); z = fmaf(o[1], wa.y, z);
            z = fmaf(o[2], wa.z, z); z = fmaf(o[3], wa.w, z);
            z = fmaf(o[4], wb.x, z); z = fmaf(o[5], wb.y, z);
            z = fmaf(o[6], wb.z, z); z = fmaf(o[7], wb.w, z);
            z = fmaf(o[8], wc.x, z); z = fmaf(o[9], wc.y, z);
            xt[i] = z * fast_sigmoid(z);             // silu
        }
        const float* w21t = s + oW21 + t * 16;       // +oo*128 is imm offset
        const float* w22t = s + oW22 + t * 16;
        #pragma unroll
        for (int oo = 0; oo < 32; ++oo) {
            const float4* w = reinterpret_cast<const float4*>(w21t + oo * 128);
            float4 w0 = w[0], w1_ = w[1], w2 = w[2], w3 = w[3];
            float a = acc21[oo];
            a = fmaf(xt[0],  w0.x, a); a = fmaf(xt[1],  w0.y, a);
            a = fmaf(xt[2],  w0.z, a); a = fmaf(xt[3],  w0.w, a);
            a = fmaf(xt[4],  w1_.x, a); a = fmaf(xt[5],  w1_.y, a);
            a = fmaf(xt[6],  w1_.z, a); a = fmaf(xt[7],  w1_.w, a);
            a = fmaf(xt[8],  w2.x, a); a = fmaf(xt[9],  w2.y, a);
            a = fmaf(xt[10], w2.z, a); a = fmaf(xt[11], w2.w, a);
            a = fmaf(xt[12], w3.x, a); a = fmaf(xt[13], w3.y, a);
            a = fmaf(xt[14], w3.z, a); a = fmaf(xt[15], w3.w, a);
            acc21[oo] = a;
        }
        #pragma unroll
        for (int oo = 0; oo < 32; ++oo) {
            const float4* w = reinterpret_cast<const float4*>(w22t + oo * 128);
            float4 w0 = w[0], w1_ = w[1], w2 = w[2], w3 = w[3];
            float a = acc22[oo];
            a = fmaf(xt[0],  w0.x, a); a = fmaf(xt[1],  w0.y, a);
            a = fmaf(xt[2],  w0.z, a); a = fmaf(xt[3],  w0.w, a);
            a = fmaf(xt[4],  w1_.x, a); a = fmaf(xt[5],  w1_.y, a);
            a = fmaf(xt[6],  w1_.z, a); a = fmaf(xt[7],  w1_.w, a);
            a = fmaf(xt[8],  w2.x, a); a = fmaf(xt[9],  w2.y, a);
            a = fmaf(xt[10], w2.z, a); a = fmaf(xt[11], w2.w, a);
            a = fmaf(xt[12], w3.x, a); a = fmaf(xt[13], w3.y, a);
            a = fmaf(xt[14], w3.z, a); a = fmaf(xt[15], w3.w, a);
            acc22[oo] = a;
        }
    }

    // Heads: unom = silu(acc21) @ W31^T + b31 ; z32 = silu(acc22) @ W32^T + b32
    float u0 = s[oB31 + 0], u1 = s[oB31 + 1], z32 = s[oB32];
    #pragma unroll
    for (int j = 0; j < 32; ++j) {
        float z = acc21[j];
        float sv = z * fast_sigmoid(z);
        u0 = fmaf(sv, s[oW31 + j],      u0);
        u1 = fmaf(sv, s[oW31 + 32 + j], u1);
    }
    #pragma unroll
    for (int j = 0; j < 32; ++j) {
        float z = acc22[j];
        float sv = z * fast_sigmoid(z);
        z32 = fmaf(sv, s[oW32 + j], z32);
    }
    const float alpha = 4.0f * fast_sigmoid(z32);

    // CBF-QP epilogue (R_SAFE = 0.8).
    const float rx = o[6], ry = o[7], vx = o[8], vy = o[9];
    const float barrier = rx * rx + ry * ry - 0.64f;
    const float lf = -2.0f * (rx * vx + ry * vy);
    const float gx = -2.0f * rx, gy = -2.0f * ry;
    const float h  = lf + alpha * barrier;
    const float gg = gx * gx + gy * gy;
    const float viol = gx * u0 + gy * u1 - h;
    float lam = 0.0f;
    if (gg > 0.0f) lam = fmaxf(viol, 0.0f) / fmaxf(gg, 1e-12f);  // v_cndmask

    float2 r;
    r.x = fmaf(-lam, gx, u0);
    r.y = fmaf(-lam, gy, u1);
    *reinterpret_cast<float2*>(out + (size_t)row * 2) = r;
}

extern "C" void kernel_launch(void* const* d_in, const int* in_sizes, int n_in,
                              void* d_out, int out_size, void* d_ws, size_t ws_size,
                              hipStream_t stream) {
    const float* obs = (const float*)d_in[0];
    const float* W1  = (const float*)d_in[1];
    const float* b1  = (const float*)d_in[2];
    const float* W21 = (const float*)d_in[3];
    const float* b21 = (const float*)d_in[4];
    const float* W22 = (const float*)d_in[5];
    const float* b22 = (const float*)d_in[6];
    const float* W31 = (const float*)d_in[7];
    const float* b31 = (const float*)d_in[8];
    const float* W32 = (const float*)d_in[9];
    const float* b32 = (const float*)d_in[10];

    const int B = in_sizes[0] / 10;            // obs is [B,10]
    const int blocks = (B + TPB - 1) / TPB;    // B = 524288 -> 2048 blocks

    barriernet_kernel<<<blocks, TPB, 0, stream>>>(
        obs, W1, b1, W21, b21, W22, b22, W31, b31, W32, b32,
        (float*)d_out, B);
}

// Round 3
// 343.237 us; speedup vs baseline: 1.3292x; 1.0208x over previous
//
#include <hip/hip_runtime.h>

// BarrierNet fused MLP + CBF-QP filter, fp32, LDS-staged weights.
// One thread per row. All weights (~39 KB) staged into LDS once per block;
// compute reads them wave-uniform (ds broadcast, no conflicts).
//
// R3 change: __launch_bounds__(256, 4). LDS (40 KB) caps us at 4 blocks/CU
// = 4 waves/EU anyway; declaring it raises the VGPR budget to 128, which
// fits the ~110-register live set (acc21[32]+acc22[32]+xt[16]+o[10]+temps).
// R2's undeclared build chose VGPR=68 -> AGPR spill traffic (v_accvgpr_*)
// inflated VALU issue 3.5x over the 19k-cycle/wave FMA payload.

#define TPB 256

// LDS float offsets. W1 rows padded 10->12 floats so every row is 16B-aligned.
#define oW1  0        // [128][12] padded            (1536 floats)
#define oB1  1536     // [128]
#define oW21 1664     // [32][128]                   (4096)
#define oB21 5760     // [32]
#define oW22 5792     // [32][128]                   (4096)
#define oB22 9888     // [32]
#define oW31 9920     // [2][32]                     (64)
#define oB31 9984     // [2]  (+2 pad for alignment)
#define oW32 9988     // [32]
#define oB32 10020    // [1]
#define SMEM_F 10024  // 40096 bytes <= 40960 -> 4 blocks/CU (160 KiB LDS)

__device__ __forceinline__ float fast_sigmoid(float z) {
    // 1/(1+exp(-z)); v_exp_f32 + v_rcp_f32. Overflow-safe: exp->inf -> rcp->0.
    return __builtin_amdgcn_rcpf(1.0f + __expf(-z));
}

__global__ __launch_bounds__(TPB, 4) void barriernet_kernel(
    const float* __restrict__ obs,
    const float* __restrict__ W1,  const float* __restrict__ b1,
    const float* __restrict__ W21, const float* __restrict__ b21,
    const float* __restrict__ W22, const float* __restrict__ b22,
    const float* __restrict__ W31, const float* __restrict__ b31,
    const float* __restrict__ W32, const float* __restrict__ b32,
    float* __restrict__ out, int B)
{
    __shared__ float s[SMEM_F];
    const int tid = threadIdx.x;

    // Uniform control flow: clamp instead of return (v_min, no branch).
    int row = blockIdx.x * TPB + tid;
    if (row >= B) row = B - 1;

    // Per-row obs load early (5x float2; rows are 40B so 8B-aligned).
    float o[10];
    const float2* o2 = reinterpret_cast<const float2*>(obs + (size_t)row * 10);
    #pragma unroll
    for (int i = 0; i < 5; ++i) {
        float2 v = o2[i];
        o[2 * i]     = v.x;
        o[2 * i + 1] = v.y;
    }

    // ---- Cooperative weight staging into LDS ----
    for (int i = tid; i < 1280; i += TPB) s[oW1 + (i / 10) * 12 + (i % 10)] = W1[i];
    for (int i = tid; i < 128;  i += TPB) s[oB1  + i] = b1[i];
    for (int i = tid; i < 4096; i += TPB) s[oW21 + i] = W21[i];
    for (int i = tid; i < 32;   i += TPB) s[oB21 + i] = b21[i];
    for (int i = tid; i < 4096; i += TPB) s[oW22 + i] = W22[i];
    for (int i = tid; i < 32;   i += TPB) s[oB22 + i] = b22[i];
    for (int i = tid; i < 64;   i += TPB) s[oW31 + i] = W31[i];
    for (int i = tid; i < 2;    i += TPB) s[oB31 + i] = b31[i];
    for (int i = tid; i < 32;   i += TPB) s[oW32 + i] = W32[i];
    if (tid == 0) s[oB32] = b32[0];
    __syncthreads();

    // ---- Compute ----
    float acc21[32], acc22[32];
    #pragma unroll
    for (int j = 0; j < 32; ++j) acc21[j] = s[oB21 + j];
    #pragma unroll
    for (int j = 0; j < 32; ++j) acc22[j] = s[oB22 + j];

    // Layer 1 (10->128) fused with layer 2 (128->32 x2), 16 hidden units/iter.
    // t-loop rolled (I-cache); inner loops unrolled (constant reg indices,
    // LDS immediate offsets). All weight reads wave-uniform -> broadcast.
    for (int t = 0; t < 8; ++t) {
        float xt[16];
        const float* w1t = s + oW1 + t * (16 * 12);
        #pragma unroll
        for (int i = 0; i < 16; ++i) {
            const float* wr = w1t + i * 12;          // 48B stride: 16B-aligned
            float4 wa = *reinterpret_cast<const float4*>(wr);
            float4 wb = *reinterpret_cast<const float4*>(wr + 4);
            float2 wc = *reinterpret_cast<const float2*>(wr + 8);
            float z = s[oB1 + t * 16 + i];
            z = fmaf(o[0], wa.x, z); z = fmaf(o[1], wa.y, z);
            z = fmaf(o[2], wa.z, z); z = fmaf(o[3], wa.w, z);
            z = fmaf(o[4], wb.x, z); z = fmaf(o[5], wb.y, z);
            z = fmaf(o[6], wb.z, z); z = fmaf(o[7], wb.w, z);
            z = fmaf(o[8], wc.x, z); z = fmaf(o[9], wc.y, z);
            xt[i] = z * fast_sigmoid(z);             // silu
        }
        const float* w21t = s + oW21 + t * 16;       // +oo*128 folds to imm
        const float* w22t = s + oW22 + t * 16;
        #pragma unroll
        for (int oo = 0; oo < 32; ++oo) {
            const float4* w = reinterpret_cast<const float4*>(w21t + oo * 128);
            float4 w0 = w[0], w1_ = w[1], w2 = w[2], w3 = w[3];
            float a = acc21[oo];
            a = fmaf(xt[0],  w0.x, a); a = fmaf(xt[1],  w0.y, a);
            a = fmaf(xt[2],  w0.z, a); a = fmaf(xt[3],  w0.w, a);
            a = fmaf(xt[4],  w1_.x, a); a = fmaf(xt[5],  w1_.y, a);
            a = fmaf(xt[6],  w1_.z, a); a = fmaf(xt[7],  w1_.w, a);
            a = fmaf(xt[8],  w2.x, a); a = fmaf(xt[9],  w2.y, a);
            a = fmaf(xt[10], w2.z, a); a = fmaf(xt[11], w2.w, a);
            a = fmaf(xt[12], w3.x, a); a = fmaf(xt[13], w3.y, a);
            a = fmaf(xt[14], w3.z, a); a = fmaf(xt[15], w3.w, a);
            acc21[oo] = a;
        }
        #pragma unroll
        for (int oo = 0; oo < 32; ++oo) {
            const float4* w = reinterpret_cast<const float4*>(w22t + oo * 128);
            float4 w0 = w[0], w1_ = w[1], w2 = w[2], w3 = w[3];
            float a = acc22[oo];
            a = fmaf(xt[0],  w0.x, a); a = fmaf(xt[1],  w0.y, a);
            a = fmaf(xt[2],  w0.z, a); a = fmaf(xt[3],  w0.w, a);
            a = fmaf(xt[4],  w1_.x, a); a = fmaf(xt[5],  w1_.y, a);
            a = fmaf(xt[6],  w1_.z, a); a = fmaf(xt[7],  w1_.w, a);
            a = fmaf(xt[8],  w2.x, a); a = fmaf(xt[9],  w2.y, a);
            a = fmaf(xt[10], w2.z, a); a = fmaf(xt[11], w2.w, a);
            a = fmaf(xt[12], w3.x, a); a = fmaf(xt[13], w3.y, a);
            a = fmaf(xt[14], w3.z, a); a = fmaf(xt[15], w3.w, a);
            acc22[oo] = a;
        }
    }

    // Heads: unom = silu(acc21) @ W31^T + b31 ; z32 = silu(acc22) @ W32^T + b32
    float u0 = s[oB31 + 0], u1 = s[oB31 + 1], z32 = s[oB32];
    #pragma unroll
    for (int j = 0; j < 32; ++j) {
        float z = acc21[j];
        float sv = z * fast_sigmoid(z);
        u0 = fmaf(sv, s[oW31 + j],      u0);
        u1 = fmaf(sv, s[oW31 + 32 + j], u1);
    }
    #pragma unroll
    for (int j = 0; j < 32; ++j) {
        float z = acc22[j];
        float sv = z * fast_sigmoid(z);
        z32 = fmaf(sv, s[oW32 + j], z32);
    }
    const float alpha = 4.0f * fast_sigmoid(z32);

    // CBF-QP epilogue (R_SAFE = 0.8).
    const float rx = o[6], ry = o[7], vx = o[8], vy = o[9];
    const float barrier = rx * rx + ry * ry - 0.64f;
    const float lf = -2.0f * (rx * vx + ry * vy);
    const float gx = -2.0f * rx, gy = -2.0f * ry;
    const float h  = lf + alpha * barrier;
    const float gg = gx * gx + gy * gy;
    const float viol = gx * u0 + gy * u1 - h;
    float lam = 0.0f;
    if (gg > 0.0f) lam = fmaxf(viol, 0.0f) / fmaxf(gg, 1e-12f);  // v_cndmask

    float2 r;
    r.x = fmaf(-lam, gx, u0);
    r.y = fmaf(-lam, gy, u1);
    *reinterpret_cast<float2*>(out + (size_t)row * 2) = r;
}

extern "C" void kernel_launch(void* const* d_in, const int* in_sizes, int n_in,
                              void* d_out, int out_size, void* d_ws, size_t ws_size,
                              hipStream_t stream) {
    const float* obs = (const float*)d_in[0];
    const float* W1  = (const float*)d_in[1];
    const float* b1  = (const float*)d_in[2];
    const float* W21 = (const float*)d_in[3];
    const float* b21 = (const float*)d_in[4];
    const float* W22 = (const float*)d_in[5];
    const float* b22 = (const float*)d_in[6];
    const float* W31 = (const float*)d_in[7];
    const float* b31 = (const float*)d_in[8];
    const float* W32 = (const float*)d_in[9];
    const float* b32 = (const float*)d_in[10];

    const int B = in_sizes[0] / 10;            // obs is [B,10]
    const int blocks = (B + TPB - 1) / TPB;    // B = 524288 -> 2048 blocks

    barriernet_kernel<<<blocks, TPB, 0, stream>>>(
        obs, W1, b1, W21, b21, W22, b22, W31, b31, W32, b32,
        (float*)d_out, B);
}

// Round 4
// 158.611 us; speedup vs baseline: 2.8764x; 2.1640x over previous
//
#include <hip/hip_runtime.h>

// BarrierNet fused MLP + CBF-QP filter — f16 MFMA restructure.
//
// All three layers run on the matrix pipe (mfma_f32_16x16x32_f16), weights
// live as per-lane B-fragments in VGPRs (converted from fp32 once per wave),
// activations go C-layout -> A-layout via a per-wave LDS tile. Epilogue in
// fp32 from re-loaded obs. fp32 accumulate everywhere (MFMA C/D is fp32).
//
// Layouts (HW-verified, learn_hip m89/m91/m120):
//   A-frag: lane holds A[m=lane&15][k=(lane>>4)*8 + j], j=0..7
//   B-frag: lane holds B[k=(lane>>4)*8+j][n=lane&15]  (= W[n][k], W:[out,in])
//   C/D   : lane holds D[row=(lane>>4)*4+reg][col=lane&15]
//
// Register budget: w1f 32 + w2f 64 + w3f 8 + biases 13 + a2 16 + a3 8 + temps
// ~= 190 VGPR -> __launch_bounds__(256,2) (256-VGPR budget, no spills).

typedef _Float16 half8 __attribute__((ext_vector_type(8)));
typedef float floatx4 __attribute__((ext_vector_type(4)));

#define TPB   256
#define NW    4        // waves per block
#define GRID  2048
#define XSTR  136      // x-tile row stride in halfs (272 B) — conflict-free b128

__device__ __forceinline__ float fast_sigmoid(float z) {
    return __builtin_amdgcn_rcpf(1.0f + __expf(-z));
}

__device__ __forceinline__ half8 pack8(float a, float b, float c, float d,
                                       float e, float f, float g, float h) {
    half8 v;
    v[0] = (_Float16)a; v[1] = (_Float16)b; v[2] = (_Float16)c; v[3] = (_Float16)d;
    v[4] = (_Float16)e; v[5] = (_Float16)f; v[6] = (_Float16)g; v[7] = (_Float16)h;
    return v;
}

__global__ __launch_bounds__(TPB, 2) void barriernet_kernel(
    const float* __restrict__ obs,
    const float* __restrict__ W1,  const float* __restrict__ b1,
    const float* __restrict__ W21, const float* __restrict__ b21,
    const float* __restrict__ W22, const float* __restrict__ b22,
    const float* __restrict__ W31, const float* __restrict__ b31,
    const float* __restrict__ W32, const float* __restrict__ b32,
    float* __restrict__ out, int B, int iters)
{
    __shared__ _Float16 xs[NW * 16 * XSTR];   // activation transpose tiles
    __shared__ float    ep[NW * 16 * 4];      // layer-3 outputs for epilogue

    const int tid  = threadIdx.x;
    const int wave = tid >> 6;
    const int lane = tid & 63;
    const int m    = lane & 15;     // A-row / B-col / D-col index
    const int q    = lane >> 4;     // quad: k-chunk / D-row-group

    _Float16* xw  = xs + wave * 16 * XSTR;
    float*    epw = ep + wave * 16 * 4;

    // ================= per-lane weight fragments (once) =================
    // Layer 1: W1 [128][10] fp32. B-frag n = nt*16+m, k = q*8+j (k>=10 -> 0).
    half8 w1f[8]; float b1f[8];
    #pragma unroll
    for (int nt = 0; nt < 8; ++nt) {
        const float* wr = W1 + (nt * 16 + m) * 10;       // 40B rows, 8B aligned
        float f0=0,f1=0,f2=0,f3=0,f4=0,f5=0,f6=0,f7=0;
        if (q == 0) {
            float2 p0 = *(const float2*)(wr + 0);
            float2 p1 = *(const float2*)(wr + 2);
            float2 p2 = *(const float2*)(wr + 4);
            float2 p3 = *(const float2*)(wr + 6);
            f0=p0.x; f1=p0.y; f2=p1.x; f3=p1.y;
            f4=p2.x; f5=p2.y; f6=p3.x; f7=p3.y;
        } else if (q == 1) {
            float2 p = *(const float2*)(wr + 8);         // k = 8,9
            f0=p.x; f1=p.y;
        }
        w1f[nt] = pack8(f0,f1,f2,f3,f4,f5,f6,f7);
        b1f[nt] = b1[nt * 16 + m];
    }

    // Layer 2: cat[W21;W22] [64][128] fp32. n = nt2*16+m, k = kt*32+q*8+j.
    half8 w2f[4][4]; float b2f[4];
    #pragma unroll
    for (int nt2 = 0; nt2 < 4; ++nt2) {
        const int n2 = nt2 * 16 + m;
        const float* wrow = (n2 < 32) ? (W21 + n2 * 128) : (W22 + (n2 - 32) * 128);
        b2f[nt2] = (n2 < 32) ? b21[n2] : b22[n2 - 32];
        #pragma unroll
        for (int kt = 0; kt < 4; ++kt) {
            const float4* p = (const float4*)(wrow + kt * 32 + q * 8);  // 16B ok
            float4 x0 = p[0], x1 = p[1];
            w2f[nt2][kt] = pack8(x0.x,x0.y,x0.z,x0.w, x1.x,x1.y,x1.z,x1.w);
        }
    }

    // Layer 3: cat-heads [16][64]: n=0,1 -> W31 rows (k<32); n=2 -> W32 (k>=32).
    half8 w3f[2]; float b3v;
    {
        float f[8] = {0,0,0,0,0,0,0,0};
        if (m < 2) {
            const float4* p = (const float4*)(W31 + m * 32 + q * 8);
            float4 x0 = p[0], x1 = p[1];
            f[0]=x0.x; f[1]=x0.y; f[2]=x0.z; f[3]=x0.w;
            f[4]=x1.x; f[5]=x1.y; f[6]=x1.z; f[7]=x1.w;
        }
        w3f[0] = pack8(f[0],f[1],f[2],f[3],f[4],f[5],f[6],f[7]);
        float g[8] = {0,0,0,0,0,0,0,0};
        if (m == 2) {
            const float4* p = (const float4*)(W32 + q * 8);
            float4 x0 = p[0], x1 = p[1];
            g[0]=x0.x; g[1]=x0.y; g[2]=x0.z; g[3]=x0.w;
            g[4]=x1.x; g[5]=x1.y; g[6]=x1.z; g[7]=x1.w;
        }
        w3f[1] = pack8(g[0],g[1],g[2],g[3],g[4],g[5],g[6],g[7]);
        b3v = (m == 0) ? b31[0] : (m == 1) ? b31[1] : (m == 2) ? b32[0] : 0.0f;
    }

    const int tiles = (B + 15) >> 4;

    // ========================= row-tile loop =========================
    for (int it = 0; it < iters; ++it) {
        int tile = it * (GRID * NW) + blockIdx.x * NW + wave;
        if (tile >= tiles) tile = tiles - 1;               // dup work, benign
        const int rowbase = tile << 4;
        int lrow = rowbase + m;
        if (lrow >= B) lrow = B - 1;
        const float* orow = obs + (size_t)lrow * 10;

        // --- A-fragment of obs (k = q*8+j, valid k<10) ---
        float g0=0,g1=0,g2=0,g3=0,g4=0,g5=0,g6=0,g7=0;
        if (q == 0) {
            float2 p0 = *(const float2*)(orow + 0);
            float2 p1 = *(const float2*)(orow + 2);
            float2 p2 = *(const float2*)(orow + 4);
            float2 p3 = *(const float2*)(orow + 6);
            g0=p0.x; g1=p0.y; g2=p1.x; g3=p1.y;
            g4=p2.x; g5=p2.y; g6=p3.x; g7=p3.y;
        } else if (q == 1) {
            float2 p = *(const float2*)(orow + 8);
            g0=p.x; g1=p.y;
        }
        const half8 a1 = pack8(g0,g1,g2,g3,g4,g5,g6,g7);

        // --- layer 1: 8 n-tiles, bias in C-init, silu, write x-tile ---
        #pragma unroll
        for (int nt = 0; nt < 8; ++nt) {
            floatx4 z = {b1f[nt], b1f[nt], b1f[nt], b1f[nt]};
            z = __builtin_amdgcn_mfma_f32_16x16x32_f16(a1, w1f[nt], z, 0, 0, 0);
            #pragma unroll
            for (int r = 0; r < 4; ++r) {
                float zz = z[r];
                float sv = zz * fast_sigmoid(zz);
                xw[(q * 4 + r) * XSTR + nt * 16 + m] = (_Float16)sv;
            }
        }
        __syncthreads();

        // --- x-tile -> layer-2 A-fragments (ds_read_b128, conflict-free) ---
        half8 a2[4];
        #pragma unroll
        for (int kt = 0; kt < 4; ++kt)
            a2[kt] = *(const half8*)(xw + m * XSTR + kt * 32 + q * 8);
        __syncthreads();

        // --- layer 2: 4 n-tiles x 4 k-tiles, silu, write x2-tile ---
        #pragma unroll
        for (int nt2 = 0; nt2 < 4; ++nt2) {
            floatx4 z = {b2f[nt2], b2f[nt2], b2f[nt2], b2f[nt2]};
            #pragma unroll
            for (int kt = 0; kt < 4; ++kt)
                z = __builtin_amdgcn_mfma_f32_16x16x32_f16(a2[kt], w2f[nt2][kt], z, 0, 0, 0);
            #pragma unroll
            for (int r = 0; r < 4; ++r) {
                float zz = z[r];
                float sv = zz * fast_sigmoid(zz);
                xw[(q * 4 + r) * XSTR + nt2 * 16 + m] = (_Float16)sv;
            }
        }
        __syncthreads();

        // --- x2-tile -> layer-3 A-fragments, head MFMA ---
        half8 a3[2];
        #pragma unroll
        for (int kt = 0; kt < 2; ++kt)
            a3[kt] = *(const half8*)(xw + m * XSTR + kt * 32 + q * 8);

        floatx4 d = {b3v, b3v, b3v, b3v};
        d = __builtin_amdgcn_mfma_f32_16x16x32_f16(a3[0], w3f[0], d, 0, 0, 0);
        d = __builtin_amdgcn_mfma_f32_16x16x32_f16(a3[1], w3f[1], d, 0, 0, 0);

        if (m < 3) {
            #pragma unroll
            for (int r = 0; r < 4; ++r)
                epw[(q * 4 + r) * 4 + m] = d[r];
        }
        __syncthreads();

        // --- fp32 CBF-QP epilogue: lanes of quad 0, one row each ---
        if (q == 0) {
            const float u0  = epw[m * 4 + 0];
            const float u1  = epw[m * 4 + 1];
            const float z32 = epw[m * 4 + 2];
            const float alpha = 4.0f * fast_sigmoid(z32);

            const float2 rxy = *(const float2*)(orow + 6);
            const float2 vxy = *(const float2*)(orow + 8);
            const float rx = rxy.x, ry = rxy.y, vx = vxy.x, vy = vxy.y;

            const float barrier = rx * rx + ry * ry - 0.64f;   // R_SAFE^2
            const float lf = -2.0f * (rx * vx + ry * vy);
            const float gx = -2.0f * rx, gy = -2.0f * ry;
            const float h  = lf + alpha * barrier;
            const float gg = gx * gx + gy * gy;
            const float viol = gx * u0 + gy * u1 - h;
            float lam = 0.0f;
            if (gg > 0.0f) lam = fmaxf(viol, 0.0f) / fmaxf(gg, 1e-12f);

            float2 r;
            r.x = fmaf(-lam, gx, u0);
            r.y = fmaf(-lam, gy, u1);
            *(float2*)(out + (size_t)lrow * 2) = r;
        }
        __syncthreads();   // protect xs/ep before next iteration
    }
}

extern "C" void kernel_launch(void* const* d_in, const int* in_sizes, int n_in,
                              void* d_out, int out_size, void* d_ws, size_t ws_size,
                              hipStream_t stream) {
    const float* obs = (const float*)d_in[0];
    const float* W1  = (const float*)d_in[1];
    const float* b1  = (const float*)d_in[2];
    const float* W21 = (const float*)d_in[3];
    const float* b21 = (const float*)d_in[4];
    const float* W22 = (const float*)d_in[5];
    const float* b22 = (const float*)d_in[6];
    const float* W31 = (const float*)d_in[7];
    const float* b31 = (const float*)d_in[8];
    const float* W32 = (const float*)d_in[9];
    const float* b32 = (const float*)d_in[10];

    const int B = in_sizes[0] / 10;                 // obs is [B,10]
    const int tiles = (B + 15) / 16;
    const int slots = GRID * NW;
    const int iters = (tiles + slots - 1) / slots;  // B=524288 -> 4

    barriernet_kernel<<<GRID, TPB, 0, stream>>>(
        obs, W1, b1, W21, b21, W22, b22, W31, b31, W32, b32,
        (float*)d_out, B, iters);
}

// Round 5
// 148.745 us; speedup vs baseline: 3.0672x; 1.0663x over previous
//
#include <hip/hip_runtime.h>

// BarrierNet fused MLP + CBF-QP filter — f16 MFMA, barrier-free, prepacked.
//
// Kernel 1 (prep): convert fp32 weights -> per-lane f16 MFMA B-fragments +
// bias tables in d_ws (~30 KB), coalesced for the main kernel.
// Kernel 2 (main): 16 rows per wave-iteration, all three layers on
// mfma_f32_16x16x32_f16. Activation C-layout -> A-layout via *wave-private*
// LDS tiles; NO __syncthreads anywhere — intra-wave LDS RAW ordering is
// guaranteed by in-order DS completion + compiler lgkmcnt waits, so waves
// run fully decoupled (R4's 4 barriers/tile coupled 4 waves and left both
// pipes <35% busy).
//
// Layouts (HW-verified, learn_hip m89/m91/m120):
//   A-frag: lane holds A[m=lane&15][k=(lane>>4)*8 + j], j=0..7
//   B-frag: lane holds B[k=(lane>>4)*8+j][n=lane&15]  (= W[n][k], W:[out,in])
//   C/D   : lane holds D[row=(lane>>4)*4+reg][col=lane&15]

typedef _Float16 half8 __attribute__((ext_vector_type(8)));
typedef float floatx4 __attribute__((ext_vector_type(4)));

#define TPB   256
#define NW    4         // waves per block
#define GRID  4096      // 4096 blocks * 4 waves = 16384 wave-slots
#define XSTR  136       // x-tile row stride in halfs (272 B, 16B-aligned rows)

// d_ws layout (bytes). Fragment region is one contiguous array of half8 in
// fragID-major order: fragID 0..7 = W1 n-tiles, 8..23 = W2 (nt2*4+kt),
// 24..25 = W3 heads; within a fragID, 64 lanes.
#define WS_FRAG 0        // 26*64 half8  = 26624 B
#define WS_B1   26624    // 8*64 float   =  2048 B   b1f[nt][lane]
#define WS_B2   28672    // 4*64 float   =  1024 B   b2f[nt2][lane]
#define WS_B3   29696    // 64 float     =   256 B   b3v[lane]

__device__ __forceinline__ float fast_sigmoid(float z) {
    return __builtin_amdgcn_rcpf(1.0f + __expf(-z));
}

// ---------------- prep: fp32 weights -> f16 fragments in ws ----------------
__global__ __launch_bounds__(256) void prep_kernel(
    const float* __restrict__ W1,  const float* __restrict__ b1,
    const float* __restrict__ W21, const float* __restrict__ b21,
    const float* __restrict__ W22, const float* __restrict__ b22,
    const float* __restrict__ W31, const float* __restrict__ b31,
    const float* __restrict__ W32, const float* __restrict__ b32,
    unsigned char* __restrict__ ws)
{
    const int tid  = blockIdx.x * 256 + threadIdx.x;
    const int lane = tid & 63;
    const int m    = lane & 15;
    const int q    = lane >> 4;

    if (tid < 26 * 64) {
        const int f = tid >> 6;
        float v[8];
        if (f < 8) {                         // layer 1: W1 [128][10], K pad->32
            const float* wr = W1 + (f * 16 + m) * 10;
            #pragma unroll
            for (int j = 0; j < 8; ++j) {
                const int k = q * 8 + j;
                v[j] = (k < 10) ? wr[k] : 0.0f;
            }
        } else if (f < 24) {                 // layer 2: cat[W21;W22] [64][128]
            const int f2 = f - 8, nt2 = f2 >> 2, kt = f2 & 3;
            const int n2 = nt2 * 16 + m;
            const float* wr = (n2 < 32) ? (W21 + n2 * 128)
                                        : (W22 + (n2 - 32) * 128);
            #pragma unroll
            for (int j = 0; j < 8; ++j) v[j] = wr[kt * 32 + q * 8 + j];
        } else if (f == 24) {                // layer 3 kt=0: W31 rows, n=0,1
            #pragma unroll
            for (int j = 0; j < 8; ++j)
                v[j] = (m < 2) ? W31[m * 32 + q * 8 + j] : 0.0f;
        } else {                             // layer 3 kt=1: W32, n=2
            #pragma unroll
            for (int j = 0; j < 8; ++j)
                v[j] = (m == 2) ? W32[q * 8 + j] : 0.0f;
        }
        half8 h;
        #pragma unroll
        for (int j = 0; j < 8; ++j) h[j] = (_Float16)v[j];
        ((half8*)(ws + WS_FRAG))[tid] = h;
    }
    if (tid < 512)
        ((float*)(ws + WS_B1))[tid] = b1[(tid >> 6) * 16 + (tid & 15)];
    if (tid < 256) {
        const int n2 = (tid >> 6) * 16 + (tid & 15);
        ((float*)(ws + WS_B2))[tid] = (n2 < 32) ? b21[n2] : b22[n2 - 32];
    }
    if (tid < 64) {
        const int mm = tid & 15;
        ((float*)(ws + WS_B3))[tid] =
            (mm == 0) ? b31[0] : (mm == 1) ? b31[1] : (mm == 2) ? b32[0] : 0.0f;
    }
}

// ------------------------------- main -------------------------------------
__global__ __launch_bounds__(TPB, 3) void barriernet_kernel(
    const float* __restrict__ obs,
    const unsigned char* __restrict__ ws,
    float* __restrict__ out, int B, int iters)
{
    __shared__ _Float16 xs[NW * 16 * XSTR];   // wave-private transpose tiles
    __shared__ float    ep[NW * 16 * 4];      // wave-private head outputs

    const int tid  = threadIdx.x;
    const int wave = tid >> 6;
    const int lane = tid & 63;
    const int m    = lane & 15;
    const int q    = lane >> 4;

    _Float16* xw  = xs + wave * 16 * XSTR;
    float*    epw = ep + wave * 16 * 4;
    _Float16* xq  = xw + q * 4 * XSTR + m;    // write base; +r*XSTR+nt*16 imm
    const half8* xr = (const half8*)(xw + m * XSTR + q * 8);  // read base

    // ---- weight fragments: 26 coalesced b128 loads + 13 bias loads ----
    const half8* wf = (const half8*)(ws + WS_FRAG);
    half8 w1f[8], w2f[16], w3f0, w3f1;
    #pragma unroll
    for (int nt = 0; nt < 8; ++nt)  w1f[nt] = wf[nt * 64 + lane];
    #pragma unroll
    for (int f2 = 0; f2 < 16; ++f2) w2f[f2] = wf[(8 + f2) * 64 + lane];
    w3f0 = wf[24 * 64 + lane];
    w3f1 = wf[25 * 64 + lane];

    const float* fB1 = (const float*)(ws + WS_B1);
    const float* fB2 = (const float*)(ws + WS_B2);
    float b1f[8], b2f[4];
    #pragma unroll
    for (int nt = 0; nt < 8; ++nt) b1f[nt] = fB1[nt * 64 + lane];
    #pragma unroll
    for (int nt2 = 0; nt2 < 4; ++nt2) b2f[nt2] = fB2[nt2 * 64 + lane];
    const float b3v = ((const float*)(ws + WS_B3))[lane];

    const int tiles = (B + 15) >> 4;

    for (int it = 0; it < iters; ++it) {
        int tile = it * (GRID * NW) + blockIdx.x * NW + wave;
        if (tile >= tiles) tile = tiles - 1;          // dup work, benign
        int lrow = (tile << 4) + m;
        if (lrow >= B) lrow = B - 1;
        const float* orow = obs + (size_t)lrow * 10;

        // --- obs A-fragment (k = q*8+j, valid k<10) ---
        float g0=0,g1=0,g2=0,g3=0,g4=0,g5=0,g6=0,g7=0;
        if (q == 0) {
            float2 p0 = *(const float2*)(orow + 0);
            float2 p1 = *(const float2*)(orow + 2);
            float2 p2 = *(const float2*)(orow + 4);
            float2 p3 = *(const float2*)(orow + 6);
            g0=p0.x; g1=p0.y; g2=p1.x; g3=p1.y;
            g4=p2.x; g5=p2.y; g6=p3.x; g7=p3.y;
        } else if (q == 1) {
            float2 p = *(const float2*)(orow + 8);
            g0=p.x; g1=p.y;
        }
        half8 a1;
        a1[0]=(_Float16)g0; a1[1]=(_Float16)g1; a1[2]=(_Float16)g2;
        a1[3]=(_Float16)g3; a1[4]=(_Float16)g4; a1[5]=(_Float16)g5;
        a1[6]=(_Float16)g6; a1[7]=(_Float16)g7;

        // --- layer 1: 8 independent MFMAs, silu, write x-tile ---
        #pragma unroll
        for (int nt = 0; nt < 8; ++nt) {
            floatx4 z = {b1f[nt], b1f[nt], b1f[nt], b1f[nt]};
            z = __builtin_amdgcn_mfma_f32_16x16x32_f16(a1, w1f[nt], z, 0, 0, 0);
            #pragma unroll
            for (int r = 0; r < 4; ++r) {
                float zz = z[r];
                xq[r * XSTR + nt * 16] = (_Float16)(zz * fast_sigmoid(zz));
            }
        }
        // (no barrier: xw is wave-private; DS ops complete in order per wave)

        // --- x-tile -> layer-2 A-fragments (ds_read_b128) ---
        half8 a2[4];
        #pragma unroll
        for (int kt = 0; kt < 4; ++kt) a2[kt] = xr[kt * 4];

        // --- layer 2: 4 n-tiles x 4 k-tiles, silu, write x2-tile ---
        #pragma unroll
        for (int nt2 = 0; nt2 < 4; ++nt2) {
            floatx4 z = {b2f[nt2], b2f[nt2], b2f[nt2], b2f[nt2]};
            #pragma unroll
            for (int kt = 0; kt < 4; ++kt)
                z = __builtin_amdgcn_mfma_f32_16x16x32_f16(a2[kt], w2f[nt2 * 4 + kt], z, 0, 0, 0);
            #pragma unroll
            for (int r = 0; r < 4; ++r) {
                float zz = z[r];
                xq[r * XSTR + nt2 * 16] = (_Float16)(zz * fast_sigmoid(zz));
            }
        }

        // --- x2-tile -> layer-3 A-fragments, heads ---
        half8 a30 = xr[0];
        half8 a31 = xr[4];
        floatx4 d = {b3v, b3v, b3v, b3v};
        d = __builtin_amdgcn_mfma_f32_16x16x32_f16(a30, w3f0, d, 0, 0, 0);
        d = __builtin_amdgcn_mfma_f32_16x16x32_f16(a31, w3f1, d, 0, 0, 0);

        if (m < 3) {
            #pragma unroll
            for (int r = 0; r < 4; ++r)
                epw[(q * 4 + r) * 4 + m] = d[r];
        }

        // --- fp32 CBF-QP epilogue: quad-0 lanes, one row each ---
        if (q == 0) {
            float4 e = ((const float4*)epw)[m];
            const float u0 = e.x, u1 = e.y, z32 = e.z;
            const float alpha = 4.0f * fast_sigmoid(z32);

            const float2 rxy = *(const float2*)(orow + 6);
            const float2 vxy = *(const float2*)(orow + 8);
            const float rx = rxy.x, ry = rxy.y, vx = vxy.x, vy = vxy.y;

            const float barrier = rx * rx + ry * ry - 0.64f;   // R_SAFE^2
            const float lf = -2.0f * (rx * vx + ry * vy);
            const float gx = -2.0f * rx, gy = -2.0f * ry;
            const float h  = lf + alpha * barrier;
            const float gg = gx * gx + gy * gy;
            const float viol = gx * u0 + gy * u1 - h;
            float lam = 0.0f;
            if (gg > 0.0f) lam = fmaxf(viol, 0.0f) / fmaxf(gg, 1e-12f);

            float2 r;
            r.x = fmaf(-lam, gx, u0);
            r.y = fmaf(-lam, gy, u1);
            *(float2*)(out + (size_t)lrow * 2) = r;
        }
    }
}

extern "C" void kernel_launch(void* const* d_in, const int* in_sizes, int n_in,
                              void* d_out, int out_size, void* d_ws, size_t ws_size,
                              hipStream_t stream) {
    const float* obs = (const float*)d_in[0];
    const float* W1  = (const float*)d_in[1];
    const float* b1  = (const float*)d_in[2];
    const float* W21 = (const float*)d_in[3];
    const float* b21 = (const float*)d_in[4];
    const float* W22 = (const float*)d_in[5];
    const float* b22 = (const float*)d_in[6];
    const float* W31 = (const float*)d_in[7];
    const float* b31 = (const float*)d_in[8];
    const float* W32 = (const float*)d_in[9];
    const float* b32 = (const float*)d_in[10];

    unsigned char* ws = (unsigned char*)d_ws;

    // prep: 26*64 fragment threads -> 7 blocks of 256
    prep_kernel<<<7, 256, 0, stream>>>(W1, b1, W21, b21, W22, b22,
                                       W31, b31, W32, b32, ws);

    const int B = in_sizes[0] / 10;                  // obs is [B,10]
    const int tiles = (B + 15) / 16;
    const int slots = GRID * NW;
    const int iters = (tiles + slots - 1) / slots;   // B=524288 -> 2

    barriernet_kernel<<<GRID, TPB, 0, stream>>>(
        obs, ws, (float*)d_out, B, iters);
}

// Round 6
// 134.268 us; speedup vs baseline: 3.3979x; 1.1078x over previous
//
#include <hip/hip_runtime.h>

// BarrierNet fused MLP + CBF-QP filter — f16 MFMA, barrier-free, prepacked.
//
// Kernel 1 (prep): convert fp32 weights -> per-lane f16 MFMA B-fragments +
// bias tables in d_ws (~30 KB), coalesced for the main kernel.
// Kernel 2 (main): 16 rows per wave-iteration, all three layers on
// mfma_f32_16x16x32_f16. Activation C-layout -> A-layout via *wave-private*
// LDS tiles; NO __syncthreads anywhere — intra-wave LDS RAW ordering is
// guaranteed by in-order DS completion + compiler lgkmcnt waits.
//
// R6: __launch_bounds__(TPB, 2). Measured across rounds:
//   (256,2) -> VGPR 112, WRITE_SIZE 4 MB (no spill)      [R4]
//   (256,3) -> VGPR 84,  WRITE_SIZE 85 MB (scratch spill) [R5]
// The 3rd-wave occupancy target forces the allocator UNDER the ~120-reg
// live set (w1f 32 + w2f 64 + w3f 8 + biases/a2) -> scratch traffic eats
// the barrier-removal win. Pin 2 waves/EU so fragments stay in registers.
//
// Layouts (HW-verified, learn_hip m89/m91/m120):
//   A-frag: lane holds A[m=lane&15][k=(lane>>4)*8 + j], j=0..7
//   B-frag: lane holds B[k=(lane>>4)*8+j][n=lane&15]  (= W[n][k], W:[out,in])
//   C/D   : lane holds D[row=(lane>>4)*4+reg][col=lane&15]

typedef _Float16 half8 __attribute__((ext_vector_type(8)));
typedef float floatx4 __attribute__((ext_vector_type(4)));

#define TPB   256
#define NW    4         // waves per block
#define GRID  4096      // 4096 blocks * 4 waves = 16384 wave-slots
#define XSTR  136       // x-tile row stride in halfs (272 B, 16B-aligned rows)

// d_ws layout (bytes). Fragment region: half8[fragID][lane], fragID 0..7 =
// W1 n-tiles, 8..23 = W2 (nt2*4+kt), 24..25 = W3 heads.
#define WS_FRAG 0        // 26*64 half8  = 26624 B
#define WS_B1   26624    // 8*64 float   =  2048 B   b1f[nt][lane]
#define WS_B2   28672    // 4*64 float   =  1024 B   b2f[nt2][lane]
#define WS_B3   29696    // 64 float     =   256 B   b3v[lane]

__device__ __forceinline__ float fast_sigmoid(float z) {
    return __builtin_amdgcn_rcpf(1.0f + __expf(-z));
}

// ---------------- prep: fp32 weights -> f16 fragments in ws ----------------
__global__ __launch_bounds__(256) void prep_kernel(
    const float* __restrict__ W1,  const float* __restrict__ b1,
    const float* __restrict__ W21, const float* __restrict__ b21,
    const float* __restrict__ W22, const float* __restrict__ b22,
    const float* __restrict__ W31, const float* __restrict__ b31,
    const float* __restrict__ W32, const float* __restrict__ b32,
    unsigned char* __restrict__ ws)
{
    const int tid  = blockIdx.x * 256 + threadIdx.x;
    const int lane = tid & 63;
    const int m    = lane & 15;
    const int q    = lane >> 4;

    if (tid < 26 * 64) {
        const int f = tid >> 6;
        float v[8];
        if (f < 8) {                         // layer 1: W1 [128][10], K pad->32
            const float* wr = W1 + (f * 16 + m) * 10;
            #pragma unroll
            for (int j = 0; j < 8; ++j) {
                const int k = q * 8 + j;
                v[j] = (k < 10) ? wr[k] : 0.0f;
            }
        } else if (f < 24) {                 // layer 2: cat[W21;W22] [64][128]
            const int f2 = f - 8, nt2 = f2 >> 2, kt = f2 & 3;
            const int n2 = nt2 * 16 + m;
            const float* wr = (n2 < 32) ? (W21 + n2 * 128)
                                        : (W22 + (n2 - 32) * 128);
            #pragma unroll
            for (int j = 0; j < 8; ++j) v[j] = wr[kt * 32 + q * 8 + j];
        } else if (f == 24) {                // layer 3 kt=0: W31 rows, n=0,1
            #pragma unroll
            for (int j = 0; j < 8; ++j)
                v[j] = (m < 2) ? W31[m * 32 + q * 8 + j] : 0.0f;
        } else {                             // layer 3 kt=1: W32, n=2
            #pragma unroll
            for (int j = 0; j < 8; ++j)
                v[j] = (m == 2) ? W32[q * 8 + j] : 0.0f;
        }
        half8 h;
        #pragma unroll
        for (int j = 0; j < 8; ++j) h[j] = (_Float16)v[j];
        ((half8*)(ws + WS_FRAG))[tid] = h;
    }
    if (tid < 512)
        ((float*)(ws + WS_B1))[tid] = b1[(tid >> 6) * 16 + (tid & 15)];
    if (tid < 256) {
        const int n2 = (tid >> 6) * 16 + (tid & 15);
        ((float*)(ws + WS_B2))[tid] = (n2 < 32) ? b21[n2] : b22[n2 - 32];
    }
    if (tid < 64) {
        const int mm = tid & 15;
        ((float*)(ws + WS_B3))[tid] =
            (mm == 0) ? b31[0] : (mm == 1) ? b31[1] : (mm == 2) ? b32[0] : 0.0f;
    }
}

// ------------------------------- main -------------------------------------
__global__ __launch_bounds__(TPB, 2) void barriernet_kernel(
    const float* __restrict__ obs,
    const unsigned char* __restrict__ ws,
    float* __restrict__ out, int B, int iters)
{
    __shared__ _Float16 xs[NW * 16 * XSTR];   // wave-private transpose tiles
    __shared__ float    ep[NW * 16 * 4];      // wave-private head outputs

    const int tid  = threadIdx.x;
    const int wave = tid >> 6;
    const int lane = tid & 63;
    const int m    = lane & 15;
    const int q    = lane >> 4;

    _Float16* xw  = xs + wave * 16 * XSTR;
    float*    epw = ep + wave * 16 * 4;
    _Float16* xq  = xw + q * 4 * XSTR + m;    // write base; +r*XSTR+nt*16 imm
    const half8* xr = (const half8*)(xw + m * XSTR + q * 8);  // read base

    // ---- weight fragments: 26 coalesced b128 loads + 13 bias loads ----
    const half8* wf = (const half8*)(ws + WS_FRAG);
    half8 w1f[8], w2f[16], w3f0, w3f1;
    #pragma unroll
    for (int nt = 0; nt < 8; ++nt)  w1f[nt] = wf[nt * 64 + lane];
    #pragma unroll
    for (int f2 = 0; f2 < 16; ++f2) w2f[f2] = wf[(8 + f2) * 64 + lane];
    w3f0 = wf[24 * 64 + lane];
    w3f1 = wf[25 * 64 + lane];

    const float* fB1 = (const float*)(ws + WS_B1);
    const float* fB2 = (const float*)(ws + WS_B2);
    float b1f[8], b2f[4];
    #pragma unroll
    for (int nt = 0; nt < 8; ++nt) b1f[nt] = fB1[nt * 64 + lane];
    #pragma unroll
    for (int nt2 = 0; nt2 < 4; ++nt2) b2f[nt2] = fB2[nt2 * 64 + lane];
    const float b3v = ((const float*)(ws + WS_B3))[lane];

    const int tiles = (B + 15) >> 4;

    for (int it = 0; it < iters; ++it) {
        int tile = it * (GRID * NW) + blockIdx.x * NW + wave;
        if (tile >= tiles) tile = tiles - 1;          // dup work, benign
        int lrow = (tile << 4) + m;
        if (lrow >= B) lrow = B - 1;
        const float* orow = obs + (size_t)lrow * 10;

        // --- obs A-fragment (k = q*8+j, valid k<10) ---
        float g0=0,g1=0,g2=0,g3=0,g4=0,g5=0,g6=0,g7=0;
        if (q == 0) {
            float2 p0 = *(const float2*)(orow + 0);
            float2 p1 = *(const float2*)(orow + 2);
            float2 p2 = *(const float2*)(orow + 4);
            float2 p3 = *(const float2*)(orow + 6);
            g0=p0.x; g1=p0.y; g2=p1.x; g3=p1.y;
            g4=p2.x; g5=p2.y; g6=p3.x; g7=p3.y;
        } else if (q == 1) {
            float2 p = *(const float2*)(orow + 8);
            g0=p.x; g1=p.y;
        }
        half8 a1;
        a1[0]=(_Float16)g0; a1[1]=(_Float16)g1; a1[2]=(_Float16)g2;
        a1[3]=(_Float16)g3; a1[4]=(_Float16)g4; a1[5]=(_Float16)g5;
        a1[6]=(_Float16)g6; a1[7]=(_Float16)g7;

        // --- layer 1: 8 independent MFMAs, silu, write x-tile ---
        #pragma unroll
        for (int nt = 0; nt < 8; ++nt) {
            floatx4 z = {b1f[nt], b1f[nt], b1f[nt], b1f[nt]};
            z = __builtin_amdgcn_mfma_f32_16x16x32_f16(a1, w1f[nt], z, 0, 0, 0);
            #pragma unroll
            for (int r = 0; r < 4; ++r) {
                float zz = z[r];
                xq[r * XSTR + nt * 16] = (_Float16)(zz * fast_sigmoid(zz));
            }
        }
        // (no barrier: xw is wave-private; DS ops complete in order per wave)

        // --- x-tile -> layer-2 A-fragments (ds_read_b128) ---
        half8 a2[4];
        #pragma unroll
        for (int kt = 0; kt < 4; ++kt) a2[kt] = xr[kt * 4];

        // --- layer 2: 4 n-tiles x 4 k-tiles, silu, write x2-tile ---
        #pragma unroll
        for (int nt2 = 0; nt2 < 4; ++nt2) {
            floatx4 z = {b2f[nt2], b2f[nt2], b2f[nt2], b2f[nt2]};
            #pragma unroll
            for (int kt = 0; kt < 4; ++kt)
                z = __builtin_amdgcn_mfma_f32_16x16x32_f16(a2[kt], w2f[nt2 * 4 + kt], z, 0, 0, 0);
            #pragma unroll
            for (int r = 0; r < 4; ++r) {
                float zz = z[r];
                xq[r * XSTR + nt2 * 16] = (_Float16)(zz * fast_sigmoid(zz));
            }
        }

        // --- x2-tile -> layer-3 A-fragments, heads ---
        half8 a30 = xr[0];
        half8 a31 = xr[4];
        floatx4 d = {b3v, b3v, b3v, b3v};
        d = __builtin_amdgcn_mfma_f32_16x16x32_f16(a30, w3f0, d, 0, 0, 0);
        d = __builtin_amdgcn_mfma_f32_16x16x32_f16(a31, w3f1, d, 0, 0, 0);

        if (m < 3) {
            #pragma unroll
            for (int r = 0; r < 4; ++r)
                epw[(q * 4 + r) * 4 + m] = d[r];
        }

        // --- fp32 CBF-QP epilogue: quad-0 lanes, one row each ---
        if (q == 0) {
            float4 e = ((const float4*)epw)[m];
            const float u0 = e.x, u1 = e.y, z32 = e.z;
            const float alpha = 4.0f * fast_sigmoid(z32);

            const float2 rxy = *(const float2*)(orow + 6);
            const float2 vxy = *(const float2*)(orow + 8);
            const float rx = rxy.x, ry = rxy.y, vx = vxy.x, vy = vxy.y;

            const float barrier = rx * rx + ry * ry - 0.64f;   // R_SAFE^2
            const float lf = -2.0f * (rx * vx + ry * vy);
            const float gx = -2.0f * rx, gy = -2.0f * ry;
            const float h  = lf + alpha * barrier;
            const float gg = gx * gx + gy * gy;
            const float viol = gx * u0 + gy * u1 - h;
            float lam = 0.0f;
            if (gg > 0.0f) lam = fmaxf(viol, 0.0f) / fmaxf(gg, 1e-12f);

            float2 r;
            r.x = fmaf(-lam, gx, u0);
            r.y = fmaf(-lam, gy, u1);
            *(float2*)(out + (size_t)lrow * 2) = r;
        }
    }
}

extern "C" void kernel_launch(void* const* d_in, const int* in_sizes, int n_in,
                              void* d_out, int out_size, void* d_ws, size_t ws_size,
                              hipStream_t stream) {
    const float* obs = (const float*)d_in[0];
    const float* W1  = (const float*)d_in[1];
    const float* b1  = (const float*)d_in[2];
    const float* W21 = (const float*)d_in[3];
    const float* b21 = (const float*)d_in[4];
    const float* W22 = (const float*)d_in[5];
    const float* b22 = (const float*)d_in[6];
    const float* W31 = (const float*)d_in[7];
    const float* b31 = (const float*)d_in[8];
    const float* W32 = (const float*)d_in[9];
    const float* b32 = (const float*)d_in[10];

    unsigned char* ws = (unsigned char*)d_ws;

    // prep: 26*64 fragment threads -> 7 blocks of 256
    prep_kernel<<<7, 256, 0, stream>>>(W1, b1, W21, b21, W22, b22,
                                       W31, b31, W32, b32, ws);

    const int B = in_sizes[0] / 10;                  // obs is [B,10]
    const int tiles = (B + 15) / 16;
    const int slots = GRID * NW;
    const int iters = (tiles + slots - 1) / slots;   // B=524288 -> 2

    barriernet_kernel<<<GRID, TPB, 0, stream>>>(
        obs, ws, (float*)d_out, B, iters);
}

// Round 7
// 120.134 us; speedup vs baseline: 3.7976x; 1.1177x over previous
//
#include <hip/hip_runtime.h>

// BarrierNet fused MLP + CBF-QP filter — f16 MFMA, barrier-free, prepacked,
// 2-way tile ILP.
//
// Kernel 1 (prep): fp32 weights -> per-lane f16 MFMA B-fragments + bias
// tables in d_ws (~30 KB).
// Kernel 2 (main): each wave processes TWO independent 16-row tiles in
// interleaved straight-line code. Weights (104 VGPRs) are shared between the
// two tiles, so the second dependency chain costs only ~50 extra VGPRs and
// gives the scheduler a full second chain to hide LDS/MFMA/HBM latency with
// (R6 was latency-bound: VALUBusy 44%, ~1.5 resident waves/SIMD, one serial
// chain per wave). No __syncthreads: LDS tiles are wave-private, intra-wave
// DS ordering is guaranteed by in-order completion + lgkmcnt.
//
// Register ledger: w1f 32 + w2f 64 + w3f 8 + biases 13 + 2x(a1 4 + a2 16 +
// transients ~12) ~= 190 VGPR -> __launch_bounds__(256,2). R4/R5 measured:
// (256,2)->no spill; (256,3)->VGPR 84 + 85 MB scratch traffic. Keep 2.
//
// Layouts (HW-verified, learn_hip m89/m91/m120):
//   A-frag: lane holds A[m=lane&15][k=(lane>>4)*8 + j], j=0..7
//   B-frag: lane holds B[k=(lane>>4)*8+j][n=lane&15]  (= W[n][k], W:[out,in])
//   C/D   : lane holds D[row=(lane>>4)*4+reg][col=lane&15]

typedef _Float16 half8 __attribute__((ext_vector_type(8)));
typedef float floatx4 __attribute__((ext_vector_type(4)));

#define TPB   256
#define NW    4         // waves per block
#define GRID  4096      // 4096 blocks * 4 waves * 2 tiles = 32768 tiles
#define XSTR  136       // x-tile row stride in halfs (272 B, 16B-aligned rows)

// d_ws layout (bytes). Fragment region: half8[fragID][lane], fragID 0..7 =
// W1 n-tiles, 8..23 = W2 (nt2*4+kt), 24..25 = W3 heads.
#define WS_FRAG 0        // 26*64 half8  = 26624 B
#define WS_B1   26624    // 8*64 float   =  2048 B   b1f[nt][lane]
#define WS_B2   28672    // 4*64 float   =  1024 B   b2f[nt2][lane]
#define WS_B3   29696    // 64 float     =   256 B   b3v[lane]

__device__ __forceinline__ float fast_sigmoid(float z) {
    return __builtin_amdgcn_rcpf(1.0f + __expf(-z));
}

// ---------------- prep: fp32 weights -> f16 fragments in ws ----------------
__global__ __launch_bounds__(256) void prep_kernel(
    const float* __restrict__ W1,  const float* __restrict__ b1,
    const float* __restrict__ W21, const float* __restrict__ b21,
    const float* __restrict__ W22, const float* __restrict__ b22,
    const float* __restrict__ W31, const float* __restrict__ b31,
    const float* __restrict__ W32, const float* __restrict__ b32,
    unsigned char* __restrict__ ws)
{
    const int tid  = blockIdx.x * 256 + threadIdx.x;
    const int lane = tid & 63;
    const int m    = lane & 15;
    const int q    = lane >> 4;

    if (tid < 26 * 64) {
        const int f = tid >> 6;
        float v[8];
        if (f < 8) {                         // layer 1: W1 [128][10], K pad->32
            const float* wr = W1 + (f * 16 + m) * 10;
            #pragma unroll
            for (int j = 0; j < 8; ++j) {
                const int k = q * 8 + j;
                v[j] = (k < 10) ? wr[k] : 0.0f;
            }
        } else if (f < 24) {                 // layer 2: cat[W21;W22] [64][128]
            const int f2 = f - 8, nt2 = f2 >> 2, kt = f2 & 3;
            const int n2 = nt2 * 16 + m;
            const float* wr = (n2 < 32) ? (W21 + n2 * 128)
                                        : (W22 + (n2 - 32) * 128);
            #pragma unroll
            for (int j = 0; j < 8; ++j) v[j] = wr[kt * 32 + q * 8 + j];
        } else if (f == 24) {                // layer 3 kt=0: W31 rows, n=0,1
            #pragma unroll
            for (int j = 0; j < 8; ++j)
                v[j] = (m < 2) ? W31[m * 32 + q * 8 + j] : 0.0f;
        } else {                             // layer 3 kt=1: W32, n=2
            #pragma unroll
            for (int j = 0; j < 8; ++j)
                v[j] = (m == 2) ? W32[q * 8 + j] : 0.0f;
        }
        half8 h;
        #pragma unroll
        for (int j = 0; j < 8; ++j) h[j] = (_Float16)v[j];
        ((half8*)(ws + WS_FRAG))[tid] = h;
    }
    if (tid < 512)
        ((float*)(ws + WS_B1))[tid] = b1[(tid >> 6) * 16 + (tid & 15)];
    if (tid < 256) {
        const int n2 = (tid >> 6) * 16 + (tid & 15);
        ((float*)(ws + WS_B2))[tid] = (n2 < 32) ? b21[n2] : b22[n2 - 32];
    }
    if (tid < 64) {
        const int mm = tid & 15;
        ((float*)(ws + WS_B3))[tid] =
            (mm == 0) ? b31[0] : (mm == 1) ? b31[1] : (mm == 2) ? b32[0] : 0.0f;
    }
}

// ------------------------------- main -------------------------------------
__global__ __launch_bounds__(TPB, 2) void barriernet_kernel(
    const float* __restrict__ obs,
    const unsigned char* __restrict__ ws,
    float* __restrict__ out, int B)
{
    __shared__ _Float16 xs[NW * 2 * 16 * XSTR];   // wave-private, per pair-slot
    __shared__ float    ep[NW * 2 * 16 * 4];

    const int tid  = threadIdx.x;
    const int wave = tid >> 6;
    const int lane = tid & 63;
    const int m    = lane & 15;
    const int q    = lane >> 4;

    // ---- weight fragments: 26 coalesced b128 loads + 13 bias loads ----
    const half8* wf = (const half8*)(ws + WS_FRAG);
    half8 w1f[8], w2f[16], w3f0, w3f1;
    #pragma unroll
    for (int nt = 0; nt < 8; ++nt)  w1f[nt] = wf[nt * 64 + lane];
    #pragma unroll
    for (int f2 = 0; f2 < 16; ++f2) w2f[f2] = wf[(8 + f2) * 64 + lane];
    w3f0 = wf[24 * 64 + lane];
    w3f1 = wf[25 * 64 + lane];

    const float* fB1 = (const float*)(ws + WS_B1);
    const float* fB2 = (const float*)(ws + WS_B2);
    float b1f[8], b2f[4];
    #pragma unroll
    for (int nt = 0; nt < 8; ++nt) b1f[nt] = fB1[nt * 64 + lane];
    #pragma unroll
    for (int nt2 = 0; nt2 < 4; ++nt2) b2f[nt2] = fB2[nt2 * 64 + lane];
    const float b3v = ((const float*)(ws + WS_B3))[lane];

    const int tiles = (B + 15) >> 4;
    const int tbase = (blockIdx.x * NW + wave) * 2;

    // Per-pair LDS bases (wave-private slots p=0,1).
    _Float16*    xq[2];
    const half8* xr[2];
    float*       epw[2];
    #pragma unroll
    for (int p = 0; p < 2; ++p) {
        _Float16* xw = xs + (wave * 2 + p) * 16 * XSTR;
        xq[p]  = xw + q * 4 * XSTR + m;                 // write: +r*XSTR+nt*16
        xr[p]  = (const half8*)(xw + m * XSTR + q * 8); // read:  +kt*4 (half8)
        epw[p] = ep + (wave * 2 + p) * 16 * 4;
    }

    // --- obs rows + A-fragments for both tiles (loads issue back-to-back) ---
    const float* orow[2];
    half8 a1[2];
    int lrow0[2];
    #pragma unroll
    for (int p = 0; p < 2; ++p) {
        int tile = tbase + p;
        if (tile >= tiles) tile = tiles - 1;            // dup work, benign
        int lr = (tile << 4) + m;
        if (lr >= B) lr = B - 1;
        lrow0[p] = lr;
        orow[p] = obs + (size_t)lr * 10;

        float g0=0,g1=0,g2=0,g3=0,g4=0,g5=0,g6=0,g7=0;
        if (q == 0) {
            float2 p0 = *(const float2*)(orow[p] + 0);
            float2 p1 = *(const float2*)(orow[p] + 2);
            float2 p2 = *(const float2*)(orow[p] + 4);
            float2 p3 = *(const float2*)(orow[p] + 6);
            g0=p0.x; g1=p0.y; g2=p1.x; g3=p1.y;
            g4=p2.x; g5=p2.y; g6=p3.x; g7=p3.y;
        } else if (q == 1) {
            float2 pp = *(const float2*)(orow[p] + 8);
            g0=pp.x; g1=pp.y;
        }
        a1[p][0]=(_Float16)g0; a1[p][1]=(_Float16)g1;
        a1[p][2]=(_Float16)g2; a1[p][3]=(_Float16)g3;
        a1[p][4]=(_Float16)g4; a1[p][5]=(_Float16)g5;
        a1[p][6]=(_Float16)g6; a1[p][7]=(_Float16)g7;
    }

    // --- layer 1: 2x8 independent MFMAs interleaved, silu, write x-tiles ---
    #pragma unroll
    for (int nt = 0; nt < 8; ++nt) {
        #pragma unroll
        for (int p = 0; p < 2; ++p) {
            floatx4 z = {b1f[nt], b1f[nt], b1f[nt], b1f[nt]};
            z = __builtin_amdgcn_mfma_f32_16x16x32_f16(a1[p], w1f[nt], z, 0, 0, 0);
            #pragma unroll
            for (int r = 0; r < 4; ++r) {
                float zz = z[r];
                xq[p][r * XSTR + nt * 16] = (_Float16)(zz * fast_sigmoid(zz));
            }
        }
    }

    // --- x-tiles -> layer-2 A-fragments ---
    half8 a2[2][4];
    #pragma unroll
    for (int p = 0; p < 2; ++p)
        #pragma unroll
        for (int kt = 0; kt < 4; ++kt) a2[p][kt] = xr[p][kt * 4];

    // --- layer 2: 4 n-tiles x 4 k-tiles per pair, silu, write x2-tiles ---
    #pragma unroll
    for (int nt2 = 0; nt2 < 4; ++nt2) {
        #pragma unroll
        for (int p = 0; p < 2; ++p) {
            floatx4 z = {b2f[nt2], b2f[nt2], b2f[nt2], b2f[nt2]};
            #pragma unroll
            for (int kt = 0; kt < 4; ++kt)
                z = __builtin_amdgcn_mfma_f32_16x16x32_f16(a2[p][kt], w2f[nt2 * 4 + kt], z, 0, 0, 0);
            #pragma unroll
            for (int r = 0; r < 4; ++r) {
                float zz = z[r];
                xq[p][r * XSTR + nt2 * 16] = (_Float16)(zz * fast_sigmoid(zz));
            }
        }
    }

    // --- x2-tiles -> layer-3 A-fragments, heads ---
    #pragma unroll
    for (int p = 0; p < 2; ++p) {
        half8 a30 = xr[p][0];
        half8 a31 = xr[p][4];
        floatx4 d = {b3v, b3v, b3v, b3v};
        d = __builtin_amdgcn_mfma_f32_16x16x32_f16(a30, w3f0, d, 0, 0, 0);
        d = __builtin_amdgcn_mfma_f32_16x16x32_f16(a31, w3f1, d, 0, 0, 0);
        if (m < 3) {
            #pragma unroll
            for (int r = 0; r < 4; ++r)
                epw[p][(q * 4 + r) * 4 + m] = d[r];
        }
    }

    // --- fp32 CBF-QP epilogue: quad-0 lanes, one row per lane per pair ---
    #pragma unroll
    for (int p = 0; p < 2; ++p) {
        if (q == 0) {
            float4 e = ((const float4*)epw[p])[m];
            const float u0 = e.x, u1 = e.y, z32 = e.z;
            const float alpha = 4.0f * fast_sigmoid(z32);

            const float2 rxy = *(const float2*)(orow[p] + 6);
            const float2 vxy = *(const float2*)(orow[p] + 8);
            const float rx = rxy.x, ry = rxy.y, vx = vxy.x, vy = vxy.y;

            const float barrier = rx * rx + ry * ry - 0.64f;   // R_SAFE^2
            const float lf = -2.0f * (rx * vx + ry * vy);
            const float gx = -2.0f * rx, gy = -2.0f * ry;
            const float h  = lf + alpha * barrier;
            const float gg = gx * gx + gy * gy;
            const float viol = gx * u0 + gy * u1 - h;
            float lam = 0.0f;
            if (gg > 0.0f) lam = fmaxf(viol, 0.0f) / fmaxf(gg, 1e-12f);

            float2 r;
            r.x = fmaf(-lam, gx, u0);
            r.y = fmaf(-lam, gy, u1);
            *(float2*)(out + (size_t)lrow0[p] * 2) = r;
        }
    }
}

extern "C" void kernel_launch(void* const* d_in, const int* in_sizes, int n_in,
                              void* d_out, int out_size, void* d_ws, size_t ws_size,
                              hipStream_t stream) {
    const float* obs = (const float*)d_in[0];
    const float* W1  = (const float*)d_in[1];
    const float* b1  = (const float*)d_in[2];
    const float* W21 = (const float*)d_in[3];
    const float* b21 = (const float*)d_in[4];
    const float* W22 = (const float*)d_in[5];
    const float* b22 = (const float*)d_in[6];
    const float* W31 = (const float*)d_in[7];
    const float* b31 = (const float*)d_in[8];
    const float* W32 = (const float*)d_in[9];
    const float* b32 = (const float*)d_in[10];

    unsigned char* ws = (unsigned char*)d_ws;

    // prep: 26*64 fragment threads -> 7 blocks of 256
    prep_kernel<<<7, 256, 0, stream>>>(W1, b1, W21, b21, W22, b22,
                                       W31, b31, W32, b32, ws);

    const int B = in_sizes[0] / 10;                  // obs is [B,10]
    const int tiles = (B + 15) / 16;                 // 32768
    const int pairs = (tiles + 1) / 2;               // 16384
    const int grid  = (pairs + NW - 1) / NW;         // 4096

    barriernet_kernel<<<grid, TPB, 0, stream>>>(obs, ws, (float*)d_out, B);
}